// Round 2
// 349.280 us; speedup vs baseline: 1.0486x; 1.0486x over previous
//
#include <hip/hip_runtime.h>
#include <math.h>

#define NPIX 4096
#define BATCH 32
#define CDIM 256
#define SCALE_F 0.17677669529663687f   // 32^-0.5
#define EPS_F 1e-5f

typedef _Float16 f16;
typedef _Float16 f16x8 __attribute__((ext_vector_type(8)));
typedef _Float16 f16x4 __attribute__((ext_vector_type(4)));
typedef float    f32x4 __attribute__((ext_vector_type(4)));

static __device__ __forceinline__ f32x4 mfma16(f16x8 a, f16x8 b, f32x4 c) {
    return __builtin_amdgcn_mfma_f32_16x16x32_f16(a, b, c, 0, 0, 0);
}

// ---------------------------------------------------------------------------
// K0: w_qkv (384x256 fp32) -> wh (f16)
// ---------------------------------------------------------------------------
__global__ __launch_bounds__(256)
void wconv(const float* __restrict__ w, f16* __restrict__ wh)
{
    int i = blockIdx.x * 256 + threadIdx.x;      // 24576 float4 groups
    float4 v = ((const float4*)w)[i];
    f16x4 o = {(f16)v.x, (f16)v.y, (f16)v.z, (f16)v.w};
    ((f16x4*)wh)[i] = o;
}

// ---------------------------------------------------------------------------
// K1: FUSED qkv GEMM (M=384, N=64/tile x4 tiles, K=256) directly from x fp32
//  (transpose done in LDS staging), + q-softmax -> qhatT, + exp(k) -> LDS +
//  ksum atomics, + v -> LDS, + per-head 32x32 ctx partial (MFMA over n=64)
//  accumulated in regs across 4 tiles, atomically added to global ctx.
//  Grid (16 n-groups, 32 batches) = 512 blocks = 2/CU. 4 waves, wave w owns
//  rows [96w, 96w+96) (head-aligned: 96 = 3*32) and head w for ctx.
// ---------------------------------------------------------------------------
__global__ __launch_bounds__(256)
void qkv_fused(const f16* __restrict__ wh, const float* __restrict__ x,
               f16* __restrict__ qhatT, float* __restrict__ ctx,
               float* __restrict__ ksum)
{
    __shared__ __align__(16) f16 As[384 * 32];   // 24 KB, XOR-swizzled chunks
    __shared__ __align__(16) f16 Bs[64 * 32];    //  4 KB, XOR-swizzled chunks
    __shared__ __align__(16) f16 ek_s[128 * 64]; // 16 KB, XOR-swizzled chunks
    __shared__ __align__(16) f16 v_s[128 * 64];  // 16 KB  (total 60 KB)

    const int b = blockIdx.y;
    const int t = threadIdx.x;
    const int lane = t & 63, w = t >> 6;
    const int lane15 = lane & 15, lg = lane >> 4;
    const int grow = w * 96;

    const float* xb = x + (size_t)b * 256 * NPIX;
    f16* qT = qhatT + (size_t)b * NPIX * 128;

    // B staging: thread t packs 8 channels (chunk bc) of pixel bn
    const int bn = t & 63;
    const int bc = t >> 6;
    const int bsw = bn * 32 + ((bc ^ ((bn >> 1) & 3)) << 3);

    f32x4 ctxacc[2][2];
    const f32x4 z4 = {0.f, 0.f, 0.f, 0.f};
    ctxacc[0][0] = z4; ctxacc[0][1] = z4; ctxacc[1][0] = z4; ctxacc[1][1] = z4;

    for (int tile = 0; tile < 4; tile++) {
        const int n0 = blockIdx.x * 256 + tile * 64;
        f32x4 acc[6][4];
        #pragma unroll
        for (int i = 0; i < 6; i++)
            #pragma unroll
            for (int j = 0; j < 4; j++) acc[i][j] = z4;

        // preload x for ks=0 (coalesced: 64 lanes = 256B per channel row)
        float v8[8];
        #pragma unroll
        for (int m = 0; m < 8; m++)
            v8[m] = xb[(size_t)(bc * 8 + m) * NPIX + n0 + bn];

        for (int ks = 0; ks < 8; ks++) {
            const int k0 = ks * 32;
            // A staging: 384x32 f16 from wh (L2-hot), coalesced 16B/lane
            #pragma unroll
            for (int it = 0; it < 6; it++) {
                int c = t + it * 256;
                int row = c >> 2, ch = c & 3;
                *(f16x8*)&As[row * 32 + ((ch ^ ((row >> 1) & 3)) << 3)] =
                    *(const f16x8*)&wh[(size_t)row * 256 + k0 + ch * 8];
            }
            // B staging: cvt preloaded fp32 -> f16x8, one swizzled b128 write
            f16x8 bv;
            #pragma unroll
            for (int m = 0; m < 8; m++) bv[m] = (f16)v8[m];
            *(f16x8*)&Bs[bsw] = bv;
            __syncthreads();
            // async-split: issue next k-step's x loads under the MFMA phase
            if (ks < 7) {
                #pragma unroll
                for (int m = 0; m < 8; m++)
                    v8[m] = xb[(size_t)(k0 + 32 + bc * 8 + m) * NPIX + n0 + bn];
            }
            f16x8 bf[4];
            #pragma unroll
            for (int j = 0; j < 4; j++) {
                int rr = j * 16 + lane15;
                bf[j] = *(const f16x8*)&Bs[rr * 32 + ((lg ^ ((rr >> 1) & 3)) << 3)];
            }
            #pragma unroll
            for (int i = 0; i < 6; i++) {
                int rr = grow + i * 16 + lane15;
                f16x8 af = *(const f16x8*)&As[rr * 32 + ((lg ^ ((rr >> 1) & 3)) << 3)];
                #pragma unroll
                for (int j = 0; j < 4; j++)
                    acc[i][j] = mfma16(af, bf[j], acc[i][j]);
            }
            __syncthreads();
        }

        // ---- epilogue: classify fragments by global row ----
        #pragma unroll
        for (int i = 0; i < 6; i++) {
            const int rbase = grow + i * 16;
            if (rbase < 128) {
                if ((rbase & 31) == 0) {
                    // q head (frags i, i+1): softmax over d (32 rows) per pixel
                    #pragma unroll
                    for (int j = 0; j < 4; j++) {
                        float e0[2][4]; float s = 0.f;
                        #pragma unroll
                        for (int ii = 0; ii < 2; ii++)
                            #pragma unroll
                            for (int r = 0; r < 4; r++) {
                                float ev = __expf(acc[i + ii][j][r]);
                                e0[ii][r] = ev; s += ev;
                            }
                        s += __shfl_xor(s, 16); s += __shfl_xor(s, 32);
                        float inv = SCALE_F / s;
                        int n = n0 + j * 16 + lane15;
                        #pragma unroll
                        for (int ii = 0; ii < 2; ii++) {
                            int d0 = rbase + ii * 16 + lg * 4;
                            f16x4 pk;
                            #pragma unroll
                            for (int r = 0; r < 4; r++) pk[r] = (f16)(e0[ii][r] * inv);
                            *(f16x4*)(qT + (size_t)n * 128 + d0) = pk;
                        }
                    }
                }
            } else if (rbase < 256) {
                // k frag: ek=exp(k) -> LDS, row-sum -> ksum atomics
                const int kb = rbase - 128;
                #pragma unroll
                for (int r = 0; r < 4; r++) {
                    int row = kb + lg * 4 + r;
                    float p = 0.f;
                    #pragma unroll
                    for (int j = 0; j < 4; j++) {
                        float ev = __expf(acc[i][j][r]);
                        p += ev;
                        int col = j * 16 + lane15;
                        ek_s[row * 64 + ((((col >> 3) ^ (row & 7)) << 3) | (col & 7))] =
                            (f16)ev;
                    }
                    p += __shfl_xor(p, 1); p += __shfl_xor(p, 2);
                    p += __shfl_xor(p, 4); p += __shfl_xor(p, 8);
                    if (lane15 == 0) atomicAdd(&ksum[b * 128 + row], p);
                }
            } else {
                // v frag -> LDS
                const int vb = rbase - 256;
                #pragma unroll
                for (int r = 0; r < 4; r++) {
                    int row = vb + lg * 4 + r;
                    #pragma unroll
                    for (int j = 0; j < 4; j++) {
                        int col = j * 16 + lane15;
                        v_s[row * 64 + ((((col >> 3) ^ (row & 7)) << 3) | (col & 7))] =
                            (f16)acc[i][j][r];
                    }
                }
            }
        }
        __syncthreads();
        // ctx partial for head w: 32x32 over K=n=64 (2 MFMA k-steps)
        #pragma unroll
        for (int ks2 = 0; ks2 < 2; ks2++) {
            f16x8 a2[2], b2[2];
            #pragma unroll
            for (int i2 = 0; i2 < 2; i2++) {
                int row = w * 32 + i2 * 16 + lane15;
                int off = row * 64 + (((ks2 * 4 + lg) ^ (row & 7)) << 3);
                a2[i2] = *(const f16x8*)&ek_s[off];
                b2[i2] = *(const f16x8*)&v_s[off];
            }
            #pragma unroll
            for (int i2 = 0; i2 < 2; i2++)
                #pragma unroll
                for (int j2 = 0; j2 < 2; j2++)
                    ctxacc[i2][j2] = mfma16(a2[i2], b2[j2], ctxacc[i2][j2]);
        }
        // no sync needed: next tile's first __syncthreads() orders these reads
        // before ek_s/v_s are rewritten (As/Bs staging touches other arrays)
    }

    // ctx[bh][d][e] += partials (ctx is 512 KB, L2-resident; 16 blocks/batch
    // contend per address)
    float* cg = ctx + ((size_t)b * 4 + w) * 1024;
    #pragma unroll
    for (int i2 = 0; i2 < 2; i2++)
        #pragma unroll
        for (int j2 = 0; j2 < 2; j2++)
            #pragma unroll
            for (int r = 0; r < 4; r++)
                atomicAdd(&cg[(i2 * 16 + lg * 4 + r) * 32 + j2 * 16 + lane15],
                          ctxacc[i2][j2][r]);
}

// ---------------------------------------------------------------------------
// K4: W_eff[b][o][h*32+d] = sum_e w_out[o][h*32+e] * ctx[b,h,d,e]/ksum[d] (f16)
// ---------------------------------------------------------------------------
__global__ __launch_bounds__(256)
void weff_kernel(const float* __restrict__ wout, const float* __restrict__ ctx,
                 const float* __restrict__ ksum, f16* __restrict__ weff)
{
    const int bh = blockIdx.x;                  // 0..127
    const int b = bh >> 2, h = bh & 3;
    __shared__ float cs[1024];
    __shared__ float inv_s[32];
    const int t = threadIdx.x;                  // t = output channel o
    for (int i = t; i < 1024; i += 256) cs[i] = ctx[(size_t)bh * 1024 + i];
    if (t < 32) inv_s[t] = 1.f / ksum[b * 128 + h * 32 + t];
    __syncthreads();
    float acc[32] = {};
    const float* wrow = wout + (size_t)t * 128 + h * 32;
    for (int e = 0; e < 32; e++) {
        float wv = wrow[e];
        #pragma unroll
        for (int d = 0; d < 32; d++) acc[d] += wv * cs[d * 32 + e];
    }
    f16* wo = weff + ((size_t)b * 256 + t) * 128 + h * 32;
    #pragma unroll
    for (int d = 0; d < 32; d++) wo[d] = (f16)(acc[d] * inv_s[d]);
}

// ---------------------------------------------------------------------------
// K5: out = LN(weff[b](256x128) @ qhatT^T + b_out)*g + b ; MFMA, 256x128 tile.
// ---------------------------------------------------------------------------
__global__ __launch_bounds__(256)
void out_mfma_ln(const f16* __restrict__ weff, const f16* __restrict__ qhatT,
                 const float* __restrict__ bias, const float* __restrict__ g,
                 const float* __restrict__ bb, float* __restrict__ out)
{
    __shared__ __align__(16) f16 As2[256 * 32];   // 16 KB
    __shared__ __align__(16) f16 Bs2[128 * 32];   // 8 KB
    __shared__ float pb[256], pg[256], pbb[256];
    __shared__ float lds_s[4][128], lds_s2[4][128];
    const int b = blockIdx.y;
    const int tileN = blockIdx.x * 128;
    const int t = threadIdx.x;
    const int lane = t & 63, w = t >> 6;
    const int lane15 = lane & 15, lg = lane >> 4;
    pb[t] = bias[t]; pg[t] = g[t]; pbb[t] = bb[t];
    const f16* Aw = weff + (size_t)b * 256 * 128;
    const f16* Bw = qhatT + (size_t)b * NPIX * 128;
    f32x4 acc[4][8];
    const f32x4 z4 = {0.f, 0.f, 0.f, 0.f};
    #pragma unroll
    for (int i = 0; i < 4; i++)
        #pragma unroll
        for (int j = 0; j < 8; j++) acc[i][j] = z4;

    for (int k0 = 0; k0 < 128; k0 += 32) {
        #pragma unroll
        for (int it = 0; it < 4; it++) {         // A: 1024 x 16B chunks
            int c = t + it * 256;
            int row = c >> 2, koff = (c & 3) * 8;
            *(f16x8*)&As2[row * 32 + koff] = *(const f16x8*)&Aw[(size_t)row * 128 + k0 + koff];
        }
        #pragma unroll
        for (int it = 0; it < 2; it++) {         // B: 512 x 16B chunks
            int c = t + it * 256;
            int row = c >> 2, koff = (c & 3) * 8;
            *(f16x8*)&Bs2[row * 32 + koff] =
                *(const f16x8*)&Bw[(size_t)(tileN + row) * 128 + k0 + koff];
        }
        __syncthreads();
        f16x8 af[4], bf[8];
        #pragma unroll
        for (int i = 0; i < 4; i++)
            af[i] = *(const f16x8*)&As2[(w * 64 + i * 16 + lane15) * 32 + lg * 8];
        #pragma unroll
        for (int j = 0; j < 8; j++)
            bf[j] = *(const f16x8*)&Bs2[(j * 16 + lane15) * 32 + lg * 8];
        #pragma unroll
        for (int i = 0; i < 4; i++)
            #pragma unroll
            for (int j = 0; j < 8; j++)
                acc[i][j] = mfma16(af[i], bf[j], acc[i][j]);
        __syncthreads();
    }
    // + bias
    #pragma unroll
    for (int i = 0; i < 4; i++)
        #pragma unroll
        for (int r = 0; r < 4; r++) {
            float bo = pb[w * 64 + i * 16 + lg * 4 + r];
            #pragma unroll
            for (int j = 0; j < 8; j++) acc[i][j][r] += bo;
        }
    // per-column stats (over this wave's 64 rows), then cross-wave via LDS
    #pragma unroll
    for (int j = 0; j < 8; j++) {
        float s = 0.f, s2 = 0.f;
        #pragma unroll
        for (int i = 0; i < 4; i++)
            #pragma unroll
            for (int r = 0; r < 4; r++) { float v = acc[i][j][r]; s += v; s2 += v * v; }
        s += __shfl_xor(s, 16);  s += __shfl_xor(s, 32);
        s2 += __shfl_xor(s2, 16); s2 += __shfl_xor(s2, 32);
        if (lg == 0) { lds_s[w][j * 16 + lane15] = s; lds_s2[w][j * 16 + lane15] = s2; }
    }
    __syncthreads();
    float mean[8], rstd[8];
    #pragma unroll
    for (int j = 0; j < 8; j++) {
        int col = j * 16 + lane15;
        float S = lds_s[0][col] + lds_s[1][col] + lds_s[2][col] + lds_s[3][col];
        float S2 = lds_s2[0][col] + lds_s2[1][col] + lds_s2[2][col] + lds_s2[3][col];
        float mn = S * (1.f / 256.f);
        mean[j] = mn;
        rstd[j] = rsqrtf(S2 * (1.f / 256.f) - mn * mn + EPS_F);
    }
    float* ob = out + (size_t)b * CDIM * NPIX;
    #pragma unroll
    for (int i = 0; i < 4; i++)
        #pragma unroll
        for (int r = 0; r < 4; r++) {
            int row = w * 64 + i * 16 + lg * 4 + r;
            float gm = pg[row], bt = pbb[row];
            #pragma unroll
            for (int j = 0; j < 8; j++)
                ob[(size_t)row * NPIX + tileN + j * 16 + lane15] =
                    (acc[i][j][r] - mean[j]) * rstd[j] * gm + bt;
        }
}

extern "C" void kernel_launch(void* const* d_in, const int* in_sizes, int n_in,
                              void* d_out, int out_size, void* d_ws, size_t ws_size,
                              hipStream_t stream)
{
    const float* x     = (const float*)d_in[0];
    const float* w_qkv = (const float*)d_in[1];
    const float* w_out = (const float*)d_in[2];
    const float* b_out = (const float*)d_in[3];
    const float* g     = (const float*)d_in[4];
    const float* bvec  = (const float*)d_in[5];
    float* out = (float*)d_out;

    // ws layout (bytes), total 36,388,864 B = 34.7 MiB:
    char* wsb = (char*)d_ws;
    f16*   qhatT = (f16*)wsb;                    // 33,554,432
    float* ctx   = (float*)(wsb + 33554432);     //    524,288
    float* ksum  = (float*)(wsb + 34078720);     //     16,384
    f16*   weff  = (f16*)(wsb + 34095104);       //  2,097,152
    f16*   wh    = (f16*)(wsb + 36192256);       //    196,608

    hipMemsetAsync(ctx, 0, 540672, stream);      // ctx + ksum (adjacent)
    wconv<<<96, 256, 0, stream>>>(w_qkv, wh);
    qkv_fused<<<dim3(16, BATCH), 256, 0, stream>>>(wh, x, qhatT, ctx, ksum);
    weff_kernel<<<128, 256, 0, stream>>>(w_out, ctx, ksum, weff);
    out_mfma_ln<<<dim3(32, BATCH), 256, 0, stream>>>(weff, qhatT, b_out, g, bvec, out);
}